// Round 5
// baseline (1589.372 us; speedup 1.0000x reference)
//
#include <hip/hip_runtime.h>
#include <hip/hip_bf16.h>

// DetProposalVGHead on MI355X.
// fused = [v, p, v*p, v-p]  =>  fused@W1 = v@(Wa+Wd) + p@(Wb-Wd) + (v*p)@Wc
// (never materialize the [B,P,N,4R] fused tensor).
//
// Round-5 change (ONLY the top-k rule): rounds 2/3/4 failed with the
// bit-identical output-3 error across fp32/mixed/full-fp64 ranking chains ->
// my ordering == true ordering, so the mismatch is the reference's DISCRETE
// tie resolution: jax.lax.top_k is stable (equal values -> lower index first)
// and an fp32-precision reference can see ties where exact values differ by
// <~1.2e-7. Top-k now treats candidates within EPS=2.5e-7 of the max as tied
// and picks the LOWEST index, i.e. top_k semantics on an fp32-precision view
// of the fp64-exact logits. Everything else is byte-identical to round 4
// (outputs 0/1/2 passed there).

namespace {

constexpr int Nc_   = 256;    // boxes
constexpr int Dc    = 2048;
constexpr int Rc    = 1024;
constexpr int TOPN  = 16;
constexpr int HS    = 256;    // per-head hidden width
constexpr int HO    = 512;    // combined (sim|reg) hidden, stage-2 only
constexpr int BPc   = 64;     // B*P
constexpr int PAIRS1 = 16384; // B*P*N
constexpr int PAIRS2 = 1024;  // B*P*topN

__device__ __forceinline__ float  leaky01f(float x)  { return x > 0.f ? x : 0.01f * x; }
__device__ __forceinline__ double leaky01d(double x) { return x > 0.0 ? x : 0.01  * x; }

// ---------------------------------------------------------------------------
// fp64-accumulate GEMM: C = act(A @ W + bias). BM=BN=64, BK=16, TM=TN=4.
// TA/TW in {float,double}; writes C64 and/or C32. Dims must be multiples of 64/16.
// ---------------------------------------------------------------------------
template <typename TA, typename TW, bool ST64, bool ST32, bool LEAKY>
__global__ __launch_bounds__(256) void dgemm64_kernel(
    const TA* __restrict__ A, const TW* __restrict__ W, const float* __restrict__ bias,
    double* __restrict__ C64, float* __restrict__ C32, int M, int N, int K)
{
  __shared__ double As[16][64];
  __shared__ double Bs[16][64];
  const int t = threadIdx.x, tx = t & 15, ty = t >> 4;
  const int row0 = blockIdx.y * 64, col0 = blockIdx.x * 64;
  double acc[4][4] = {};

  for (int k0 = 0; k0 < K; k0 += 16) {
    {
      int mm = t >> 2, kq = (t & 3) * 4;
      const TA* src = A + (size_t)(row0 + mm) * K + k0 + kq;
      double v0, v1, v2, v3;
      if constexpr (sizeof(TA) == 4) {
        float4 f = *(const float4*)src; v0 = f.x; v1 = f.y; v2 = f.z; v3 = f.w;
      } else {
        const double2* d = (const double2*)src;
        double2 a = d[0], b = d[1]; v0 = a.x; v1 = a.y; v2 = b.x; v3 = b.y;
      }
      As[kq + 0][mm] = v0; As[kq + 1][mm] = v1; As[kq + 2][mm] = v2; As[kq + 3][mm] = v3;
    }
    {
      int kk = t >> 4, nq = (t & 15) * 4;
      const TW* src = W + (size_t)(k0 + kk) * N + col0 + nq;
      if constexpr (sizeof(TW) == 4) {
        float4 f = *(const float4*)src;
        Bs[kk][nq] = f.x; Bs[kk][nq + 1] = f.y; Bs[kk][nq + 2] = f.z; Bs[kk][nq + 3] = f.w;
      } else {
        const double2* d = (const double2*)src;
        double2 a = d[0], b = d[1];
        Bs[kk][nq] = a.x; Bs[kk][nq + 1] = a.y; Bs[kk][nq + 2] = b.x; Bs[kk][nq + 3] = b.y;
      }
    }
    __syncthreads();
#pragma unroll
    for (int kk = 0; kk < 16; ++kk) {
      double a[4], b[4];
#pragma unroll
      for (int i = 0; i < 4; ++i) a[i] = As[kk][ty * 4 + i];
#pragma unroll
      for (int j = 0; j < 4; ++j) b[j] = Bs[kk][tx * 4 + j];
#pragma unroll
      for (int i = 0; i < 4; ++i)
#pragma unroll
        for (int j = 0; j < 4; ++j) acc[i][j] = fma(a[i], b[j], acc[i][j]);
    }
    __syncthreads();
  }

#pragma unroll
  for (int i = 0; i < 4; ++i) {
    int r = row0 + ty * 4 + i;
#pragma unroll
    for (int j = 0; j < 4; ++j) {
      int c = col0 + tx * 4 + j;
      double v = acc[i][j];
      if (bias) v += (double)bias[c];
      if constexpr (LEAKY) v = leaky01d(v);
      if constexpr (ST64) C64[(size_t)r * N + c] = v;
      if constexpr (ST32) C32[(size_t)r * N + c] = (float)v;
    }
  }
}

// ---------------------------------------------------------------------------
// fp64 pair GEMM (stage-1 sim half): H[pair,c] = leaky((vis64[vr]*phr[pr])@W
//                                               + Xv[vr] + Xp[pr] + b1). N=HS.
// pair = bp*256 + n ; vr = (bp>>4)*256 + n ; pr = bp.
// ---------------------------------------------------------------------------
__global__ __launch_bounds__(256) void pair64_kernel(
    const double* __restrict__ vis, const float* __restrict__ phr,
    const double* __restrict__ W, const double* __restrict__ Xv,
    const double* __restrict__ Xp, const double* __restrict__ b1,
    double* __restrict__ H)
{
  __shared__ double As[16][64];
  __shared__ double Bs[16][64];
  const int t = threadIdx.x, tx = t & 15, ty = t >> 4;
  const int row0 = blockIdx.y * 64, col0 = blockIdx.x * 64;
  double acc[4][4] = {};

  for (int k0 = 0; k0 < Rc; k0 += 16) {
    {
      int mm = t >> 2, kq = (t & 3) * 4;
      int m = row0 + mm, bp = m >> 8;
      int vr = ((bp >> 4) << 8) | (m & 255), pr = bp;
      const double2* vd = (const double2*)(vis + (size_t)vr * Rc + k0 + kq);
      double2 a = vd[0], b = vd[1];
      float4 p = *(const float4*)(phr + (size_t)pr * Rc + k0 + kq);
      As[kq + 0][mm] = a.x * (double)p.x; As[kq + 1][mm] = a.y * (double)p.y;
      As[kq + 2][mm] = b.x * (double)p.z; As[kq + 3][mm] = b.y * (double)p.w;
    }
    {
      int kk = t >> 4, nq = (t & 15) * 4;
      const double2* d = (const double2*)(W + (size_t)(k0 + kk) * HS + col0 + nq);
      double2 a = d[0], b = d[1];
      Bs[kk][nq] = a.x; Bs[kk][nq + 1] = a.y; Bs[kk][nq + 2] = b.x; Bs[kk][nq + 3] = b.y;
    }
    __syncthreads();
#pragma unroll
    for (int kk = 0; kk < 16; ++kk) {
      double a[4], b[4];
#pragma unroll
      for (int i = 0; i < 4; ++i) a[i] = As[kk][ty * 4 + i];
#pragma unroll
      for (int j = 0; j < 4; ++j) b[j] = Bs[kk][tx * 4 + j];
#pragma unroll
      for (int i = 0; i < 4; ++i)
#pragma unroll
        for (int j = 0; j < 4; ++j) acc[i][j] = fma(a[i], b[j], acc[i][j]);
    }
    __syncthreads();
  }

#pragma unroll
  for (int i = 0; i < 4; ++i) {
    int r = row0 + ty * 4 + i, bp = r >> 8;
    int vr = ((bp >> 4) << 8) | (r & 255), pr = bp;
#pragma unroll
    for (int j = 0; j < 4; ++j) {
      int c = col0 + tx * 4 + j;
      double v = acc[i][j] + Xv[(size_t)vr * HS + c] + Xp[(size_t)pr * HS + c] + b1[c];
      H[(size_t)r * HS + c] = leaky01d(v);
    }
  }
}

// ---------------------------------------------------------------------------
// fp32 tiled GEMM (value-only paths): C = act(A@W + bias).
// ---------------------------------------------------------------------------
template <int BM, int BN, int BK, int TM, int TN>
__global__ __launch_bounds__(256) void sgemm_kernel(
    const float* __restrict__ A, const float* __restrict__ W,
    const float* __restrict__ bias, float* __restrict__ C,
    int M, int Nc, int K, int leaky)
{
  constexpr int THREADS = (BM / TM) * (BN / TN);
  static_assert(THREADS == 256, "block must be 256");
  __shared__ float As[BK][BM];
  __shared__ float Bs[BK][BN];

  const int t = threadIdx.x;
  const int tx = t % (BN / TN), ty = t / (BN / TN);
  const int row0 = blockIdx.y * BM, col0 = blockIdx.x * BN;
  float acc[TM][TN] = {};

  for (int k0 = 0; k0 < K; k0 += BK) {
    constexpr int AV = BM * BK / 4 / THREADS;
#pragma unroll
    for (int p_ = 0; p_ < AV; ++p_) {
      int f = p_ * THREADS + t;
      int mm = f / (BK / 4), kq = (f % (BK / 4)) * 4;
      float4 a4 = *(const float4*)(A + (size_t)(row0 + mm) * K + k0 + kq);
      As[kq + 0][mm] = a4.x; As[kq + 1][mm] = a4.y;
      As[kq + 2][mm] = a4.z; As[kq + 3][mm] = a4.w;
    }
    constexpr int BV = BK * BN / 4 / THREADS;
#pragma unroll
    for (int p_ = 0; p_ < BV; ++p_) {
      int f = p_ * THREADS + t;
      int nq = (f % (BN / 4)) * 4, kk = f / (BN / 4);
      *(float4*)&Bs[kk][nq] = *(const float4*)(W + (size_t)(k0 + kk) * Nc + col0 + nq);
    }
    __syncthreads();
#pragma unroll
    for (int kk = 0; kk < BK; ++kk) {
      float a[TM], bb[TN];
#pragma unroll
      for (int i = 0; i < TM; i += 4) {
        float4 v = *(const float4*)&As[kk][ty * TM + i];
        a[i] = v.x; a[i + 1] = v.y; a[i + 2] = v.z; a[i + 3] = v.w;
      }
#pragma unroll
      for (int j = 0; j < TN; j += 4) {
        float4 v = *(const float4*)&Bs[kk][tx * TN + j];
        bb[j] = v.x; bb[j + 1] = v.y; bb[j + 2] = v.z; bb[j + 3] = v.w;
      }
#pragma unroll
      for (int i = 0; i < TM; ++i)
#pragma unroll
        for (int j = 0; j < TN; ++j) acc[i][j] = fmaf(a[i], bb[j], acc[i][j]);
    }
    __syncthreads();
  }

#pragma unroll
  for (int i = 0; i < TM; ++i) {
    int r = row0 + ty * TM + i;
#pragma unroll
    for (int j = 0; j < TN; j += 4) {
      int c = col0 + tx * TN + j;
      float4 o;
      o.x = acc[i][j]; o.y = acc[i][j + 1]; o.z = acc[i][j + 2]; o.w = acc[i][j + 3];
      if (bias) {
        float4 bv = *(const float4*)(bias + c);
        o.x += bv.x; o.y += bv.y; o.z += bv.z; o.w += bv.w;
      }
      if (leaky) { o.x = leaky01f(o.x); o.y = leaky01f(o.y); o.z = leaky01f(o.z); o.w = leaky01f(o.w); }
      *(float4*)(C + (size_t)r * Nc + c) = o;
    }
  }
}

// ---------------------------------------------------------------------------
// fp32 pair GEMM (reg half stage-1, combined stage-2). TVIS = float|double.
// ---------------------------------------------------------------------------
template <int BM, int BN, int BK, int TM, int TN, int STAGE, int NCOL, typename TVIS>
__global__ __launch_bounds__(256) void pair_gemm_kernel(
    const TVIS* __restrict__ vis, const float* __restrict__ phr,
    const float* __restrict__ Wvp, const float* __restrict__ Xv,
    const float* __restrict__ Xp, const float* __restrict__ b1c,
    float* __restrict__ Hout, int M)
{
  constexpr int THREADS = (BM / TM) * (BN / TN);
  static_assert(THREADS == 256, "block must be 256");
  __shared__ float As[BK][BM];
  __shared__ float Bs[BK][BN];

  const int t = threadIdx.x;
  const int tx = t % (BN / TN), ty = t / (BN / TN);
  const int row0 = blockIdx.y * BM, col0 = blockIdx.x * BN;
  float acc[TM][TN] = {};

  for (int k0 = 0; k0 < Rc; k0 += BK) {
    constexpr int AV = BM * BK / 4 / THREADS;
#pragma unroll
    for (int p_ = 0; p_ < AV; ++p_) {
      int f = p_ * THREADS + t;
      int mm = f / (BK / 4), kq = (f % (BK / 4)) * 4;
      int m = row0 + mm;
      int vr, pr;
      if (STAGE == 1) { int bp = m >> 8; pr = bp; vr = ((bp >> 4) << 8) | (m & 255); }
      else            { vr = m; pr = m >> 4; }
      float4 v4;
      if constexpr (sizeof(TVIS) == 8) {
        const double2* d = (const double2*)(vis + (size_t)vr * Rc + k0 + kq);
        double2 a = d[0], b = d[1];
        v4 = make_float4((float)a.x, (float)a.y, (float)b.x, (float)b.y);
      } else {
        v4 = *(const float4*)((const float*)vis + (size_t)vr * Rc + k0 + kq);
      }
      float4 p4 = *(const float4*)(phr + (size_t)pr * Rc + k0 + kq);
      As[kq + 0][mm] = v4.x * p4.x; As[kq + 1][mm] = v4.y * p4.y;
      As[kq + 2][mm] = v4.z * p4.z; As[kq + 3][mm] = v4.w * p4.w;
    }
    constexpr int BV = BK * BN / 4 / THREADS;
#pragma unroll
    for (int p_ = 0; p_ < BV; ++p_) {
      int f = p_ * THREADS + t;
      int nq = (f % (BN / 4)) * 4, kk = f / (BN / 4);
      *(float4*)&Bs[kk][nq] = *(const float4*)(Wvp + (size_t)(k0 + kk) * NCOL + col0 + nq);
    }
    __syncthreads();
#pragma unroll
    for (int kk = 0; kk < BK; ++kk) {
      float a[TM], bb[TN];
#pragma unroll
      for (int i = 0; i < TM; i += 4) {
        float4 v = *(const float4*)&As[kk][ty * TM + i];
        a[i] = v.x; a[i + 1] = v.y; a[i + 2] = v.z; a[i + 3] = v.w;
      }
#pragma unroll
      for (int j = 0; j < TN; j += 4) {
        float4 v = *(const float4*)&Bs[kk][tx * TN + j];
        bb[j] = v.x; bb[j + 1] = v.y; bb[j + 2] = v.z; bb[j + 3] = v.w;
      }
#pragma unroll
      for (int i = 0; i < TM; ++i)
#pragma unroll
        for (int j = 0; j < TN; ++j) acc[i][j] = fmaf(a[i], bb[j], acc[i][j]);
    }
    __syncthreads();
  }

#pragma unroll
  for (int i = 0; i < TM; ++i) {
    int r = row0 + ty * TM + i;
    int vr, pr;
    if (STAGE == 1) { int bp = r >> 8; pr = bp; vr = ((bp >> 4) << 8) | (r & 255); }
    else            { vr = r; pr = r >> 4; }
#pragma unroll
    for (int j = 0; j < TN; j += 4) {
      int c = col0 + tx * TN + j;
      float4 xv = *(const float4*)(Xv + (size_t)vr * NCOL + c);
      float4 xp = *(const float4*)(Xp + (size_t)pr * NCOL + c);
      float4 bv = *(const float4*)(b1c + c);
      float4 o;
      o.x = leaky01f(acc[i][j]     + xv.x + xp.x + bv.x);
      o.y = leaky01f(acc[i][j + 1] + xv.y + xp.y + bv.y);
      o.z = leaky01f(acc[i][j + 2] + xv.z + xp.z + bv.z);
      o.w = leaky01f(acc[i][j + 3] + xv.w + xp.w + bv.w);
      *(float4*)(Hout + (size_t)r * NCOL + c) = o;
    }
  }
}

// --- weight prep -----------------------------------------------------------
__global__ __launch_bounds__(256) void prep_sim64_kernel(
    const float* __restrict__ w1, const float* __restrict__ b1,
    double* __restrict__ Wv, double* __restrict__ Wp, double* __restrict__ Wvp,
    double* __restrict__ bO)
{
  int idx = blockIdx.x * 256 + threadIdx.x;  // Rc*HS = 262144
  int r = idx >> 8, c = idx & 255;
  double wa = (double)w1[(size_t)(0 * Rc + r) * 256 + c];
  double wb = (double)w1[(size_t)(1 * Rc + r) * 256 + c];
  double wc = (double)w1[(size_t)(2 * Rc + r) * 256 + c];
  double wd = (double)w1[(size_t)(3 * Rc + r) * 256 + c];
  Wv[idx] = wa + wd; Wp[idx] = wb - wd; Wvp[idx] = wc;
  if (r == 0) bO[c] = (double)b1[c];
}

__global__ __launch_bounds__(256) void prep_reg32_kernel(
    const float* __restrict__ w1, const float* __restrict__ b1,
    float* __restrict__ Wv, float* __restrict__ Wp, float* __restrict__ Wvp,
    float* __restrict__ bO)
{
  int idx = blockIdx.x * 256 + threadIdx.x;
  int r = idx >> 8, c = idx & 255;
  float wa = w1[(size_t)(0 * Rc + r) * 256 + c];
  float wb = w1[(size_t)(1 * Rc + r) * 256 + c];
  float wc = w1[(size_t)(2 * Rc + r) * 256 + c];
  float wd = w1[(size_t)(3 * Rc + r) * 256 + c];
  Wv[idx] = wa + wd; Wp[idx] = wb - wd; Wvp[idx] = wc;
  if (r == 0) bO[c] = b1[c];
}

__global__ __launch_bounds__(256) void prep_t_kernel(
    const float* __restrict__ simw1, const float* __restrict__ regw1,
    const float* __restrict__ simb1, const float* __restrict__ regb1,
    float* __restrict__ Wv, float* __restrict__ Wp, float* __restrict__ Wvp,
    float* __restrict__ b1c)
{
  int idx = blockIdx.x * 256 + threadIdx.x;  // Rc*HO = 524288
  int r = idx >> 9, j = idx & (HO - 1);
  const float* w1 = (j < 256) ? simw1 : regw1;
  int c = j & 255;
  float wa = w1[(size_t)(0 * Rc + r) * 256 + c];
  float wb = w1[(size_t)(1 * Rc + r) * 256 + c];
  float wc = w1[(size_t)(2 * Rc + r) * 256 + c];
  float wd = w1[(size_t)(3 * Rc + r) * 256 + c];
  Wv[idx] = wa + wd; Wp[idx] = wb - wd; Wvp[idx] = wc;
  if (r == 0) b1c[j] = (j < 256) ? simb1[c] : regb1[c];
}

// --- second layers ---------------------------------------------------------
__global__ __launch_bounds__(256) void layer2_sim64_kernel(
    const double* __restrict__ h, const float* __restrict__ sw2,
    const float* __restrict__ sb2, double* __restrict__ out, int M)
{
  int wave = (blockIdx.x * blockDim.x + threadIdx.x) >> 6, lane = threadIdx.x & 63;
  if (wave >= M) return;
  const double* hr = h + (size_t)wave * HS + lane * 4;
  double2 h0 = *(const double2*)hr, h1 = *(const double2*)(hr + 2);
  float4 w = *(const float4*)(sw2 + lane * 4);
  double s = h0.x * (double)w.x + h0.y * (double)w.y + h1.x * (double)w.z + h1.y * (double)w.w;
#pragma unroll
  for (int off = 32; off; off >>= 1) s += __shfl_xor(s, off);
  if (lane == 0) out[wave] = s + (double)sb2[0];
}

__global__ __launch_bounds__(256) void layer2_reg32_kernel(
    const float* __restrict__ h, const float* __restrict__ rw2,
    const float* __restrict__ rb2, float* __restrict__ reg_out, int M)
{
  int wave = (blockIdx.x * blockDim.x + threadIdx.x) >> 6, lane = threadIdx.x & 63;
  if (wave >= M) return;
  float4 hr = *(const float4*)(h + (size_t)wave * HS + lane * 4);
  float4 r0 = *(const float4*)(rw2 + (size_t)(lane * 4 + 0) * 4);
  float4 r1 = *(const float4*)(rw2 + (size_t)(lane * 4 + 1) * 4);
  float4 r2 = *(const float4*)(rw2 + (size_t)(lane * 4 + 2) * 4);
  float4 r3 = *(const float4*)(rw2 + (size_t)(lane * 4 + 3) * 4);
  float c0 = hr.x * r0.x + hr.y * r1.x + hr.z * r2.x + hr.w * r3.x;
  float c1 = hr.x * r0.y + hr.y * r1.y + hr.z * r2.y + hr.w * r3.y;
  float c2 = hr.x * r0.z + hr.y * r1.z + hr.z * r2.z + hr.w * r3.z;
  float c3 = hr.x * r0.w + hr.y * r1.w + hr.z * r2.w + hr.w * r3.w;
#pragma unroll
  for (int off = 32; off; off >>= 1) {
    c0 += __shfl_xor(c0, off); c1 += __shfl_xor(c1, off);
    c2 += __shfl_xor(c2, off); c3 += __shfl_xor(c3, off);
  }
  if (lane == 0) {
    float4 o; o.x = c0 + rb2[0]; o.y = c1 + rb2[1]; o.z = c2 + rb2[2]; o.w = c3 + rb2[3];
    *(float4*)(reg_out + (size_t)wave * 4) = o;
  }
}

__global__ __launch_bounds__(256) void layer2_t_kernel(
    const float* __restrict__ hidden,
    const float* __restrict__ sw2, const float* __restrict__ sb2,
    const float* __restrict__ rw2, const float* __restrict__ rb2,
    float* __restrict__ sim_logits, float* __restrict__ reg_out, int M)
{
  int wave = (blockIdx.x * blockDim.x + threadIdx.x) >> 6, lane = threadIdx.x & 63;
  if (wave >= M) return;
  const float* h = hidden + (size_t)wave * HO;
  float4 hs = *(const float4*)(h + lane * 4);
  float4 hr = *(const float4*)(h + 256 + lane * 4);
  float4 ws = *(const float4*)(sw2 + lane * 4);
  float s = hs.x * ws.x + hs.y * ws.y + hs.z * ws.z + hs.w * ws.w;
  float4 r0 = *(const float4*)(rw2 + (size_t)(lane * 4 + 0) * 4);
  float4 r1 = *(const float4*)(rw2 + (size_t)(lane * 4 + 1) * 4);
  float4 r2 = *(const float4*)(rw2 + (size_t)(lane * 4 + 2) * 4);
  float4 r3 = *(const float4*)(rw2 + (size_t)(lane * 4 + 3) * 4);
  float c0 = hr.x * r0.x + hr.y * r1.x + hr.z * r2.x + hr.w * r3.x;
  float c1 = hr.x * r0.y + hr.y * r1.y + hr.z * r2.y + hr.w * r3.y;
  float c2 = hr.x * r0.z + hr.y * r1.z + hr.z * r2.z + hr.w * r3.z;
  float c3 = hr.x * r0.w + hr.y * r1.w + hr.z * r2.w + hr.w * r3.w;
#pragma unroll
  for (int off = 32; off; off >>= 1) {
    s  += __shfl_xor(s, off);
    c0 += __shfl_xor(c0, off); c1 += __shfl_xor(c1, off);
    c2 += __shfl_xor(c2, off); c3 += __shfl_xor(c3, off);
  }
  if (lane == 0) {
    sim_logits[wave] = s + sb2[0];
    float4 o; o.x = c0 + rb2[0]; o.y = c1 + rb2[1]; o.z = c2 + rb2[2]; o.w = c3 + rb2[3];
    *(float4*)(reg_out + (size_t)wave * 4) = o;
  }
}

// --- softmax + top-k (fp64 values, fp32-precision tie rule) -----------------
__global__ __launch_bounds__(64) void softmax_topk64_kernel(
    const double* __restrict__ logits, float* __restrict__ sim_out,
    int* __restrict__ top_idx)
{
  int row = blockIdx.x, lane = threadIdx.x;
  double v[4];
#pragma unroll
  for (int i = 0; i < 4; ++i) v[i] = logits[row * 256 + i * 64 + lane];
  double m = fmax(fmax(v[0], v[1]), fmax(v[2], v[3]));
#pragma unroll
  for (int off = 32; off; off >>= 1) m = fmax(m, __shfl_xor(m, off));
  double e[4], ssum = 0.0;
#pragma unroll
  for (int i = 0; i < 4; ++i) { e[i] = exp(v[i] - m); ssum += e[i]; }
#pragma unroll
  for (int off = 32; off; off >>= 1) ssum += __shfl_xor(ssum, off);
#pragma unroll
  for (int i = 0; i < 4; ++i)
    sim_out[row * 256 + i * 64 + lane] = (float)(e[i] / ssum);

  // Iterative top-16. Values within EPS of the running max are treated as a
  // TIE and resolved to the LOWEST index (jax.lax.top_k stability applied to
  // an fp32-precision view: fp32 prob ties correspond to logit gaps <~1.2e-7).
  const double EPS = 2.5e-7;
  for (int it = 0; it < TOPN; ++it) {
    // 1) global max value
    double vm = fmax(fmax(v[0], v[1]), fmax(v[2], v[3]));
#pragma unroll
    for (int off = 32; off; off >>= 1) vm = fmax(vm, __shfl_xor(vm, off));
    // 2) lowest index among candidates within EPS of the max
    double thr = vm - EPS;
    int bi = 1 << 30;
#pragma unroll
    for (int i = 0; i < 4; ++i)
      if (v[i] >= thr) { int gi = i * 64 + lane; if (gi < bi) bi = gi; }
#pragma unroll
    for (int off = 32; off; off >>= 1) {
      int oi = __shfl_xor(bi, off);
      if (oi < bi) bi = oi;
    }
    if (lane == 0) top_idx[row * TOPN + it] = bi;
    if ((bi & 63) == lane) v[bi >> 6] = -1.0e30;  // mask winner
  }
}

__global__ __launch_bounds__(64) void softmax16_kernel(
    const float* __restrict__ logits, float* __restrict__ out)
{
  int row = blockIdx.x, lane = threadIdx.x;
  float v = (lane < TOPN) ? logits[row * TOPN + lane] : -1e30f;
  float m = v;
#pragma unroll
  for (int off = 8; off; off >>= 1) m = fmaxf(m, __shfl_xor(m, off));
  float e = (lane < TOPN) ? expf(v - m) : 0.f;
  float s = e;
#pragma unroll
  for (int off = 8; off; off >>= 1) s += __shfl_xor(s, off);
  if (lane < TOPN) out[row * TOPN + lane] = e / s;
}

__global__ __launch_bounds__(256) void gather_kernel(
    const float* __restrict__ box, const int* __restrict__ top_idx,
    float* __restrict__ bf_top)
{
  int pr = blockIdx.x;            // 0..1023 = (bp, t)
  int bp = pr >> 4, b = bp >> 4;
  int src = b * Nc_ + top_idx[pr];
  const float4* s = (const float4*)(box + (size_t)src * Dc);
  float4* d = (float4*)(bf_top + (size_t)pr * Dc);
  for (int i = threadIdx.x; i < Dc / 4; i += 256) d[i] = s[i];
}

}  // namespace

extern "C" void kernel_launch(void* const* d_in, const int* in_sizes, int n_in,
                              void* d_out, int out_size, void* d_ws, size_t ws_size,
                              hipStream_t stream) {
  const float* box    = (const float*)d_in[0];
  const float* phrase = (const float*)d_in[1];
  const float* ve_w1  = (const float*)d_in[2];
  const float* ve_b1  = (const float*)d_in[3];
  const float* ve_w2  = (const float*)d_in[4];
  const float* ve_b2  = (const float*)d_in[5];
  const float* sim_w1 = (const float*)d_in[6];
  const float* sim_b1 = (const float*)d_in[7];
  const float* sim_w2 = (const float*)d_in[8];
  const float* sim_b2 = (const float*)d_in[9];
  const float* reg_w1 = (const float*)d_in[10];
  const float* reg_b1 = (const float*)d_in[11];
  const float* reg_w2 = (const float*)d_in[12];
  const float* reg_b2 = (const float*)d_in[13];
  const float* vet_w1 = (const float*)d_in[14];
  const float* vet_b1 = (const float*)d_in[15];
  const float* vet_w2 = (const float*)d_in[16];
  const float* vet_b2 = (const float*)d_in[17];
  const float* simt_w1 = (const float*)d_in[18];
  const float* simt_b1 = (const float*)d_in[19];
  const float* simt_w2 = (const float*)d_in[20];
  const float* simt_b2 = (const float*)d_in[21];
  const float* regt_w1 = (const float*)d_in[22];
  const float* regt_b1 = (const float*)d_in[23];
  const float* regt_w2 = (const float*)d_in[24];
  const float* regt_b2 = (const float*)d_in[25];

  float* out = (float*)d_out;
  float* o_sim  = out;                 // [16384]
  float* o_reg  = out + PAIRS1;        // [65536]
  float* o_simt = out + 81920;         // [1024]
  float* o_regt = out + 82944;         // [4096]

  // --- workspace layout (byte offsets; peak ~54 MB) ---
  char* w = (char*)d_ws;
  double* vis64   = (double*)(w + 0);            // 8,388,608
  char*   REGA    = w + 8388608;                 // 8,388,608 region
  double* H64     = (double*)REGA;               //   phase A: fp64 layer-1 act
  double* Xv64    = (double*)REGA;               //   phase B: 2,097,152
  double* Xp64    = (double*)(REGA + 2097152);   //   131,072
  double* simlog64= (double*)(REGA + 2228224);   //   131,072
  float*  H1t     = (float*)REGA;                //   phase C (stage-2 layer-1, 4MB)
  double* WcV64   = (double*)(w + 16777216);     // 2,097,152
  double* WcP64   = (double*)(w + 18874368);     // 2,097,152
  double* WcVP64  = (double*)(w + 20971520);     // 2,097,152
  double* b1c64   = (double*)(w + 23068672);     // 2,048
  int*    topidx  = (int*)   (w + 23070720);     // 4,096
  float*  simtlog = (float*) (w + 23074816);     // 4,096
  float*  b1cr    = (float*) (w + 23078912);     // 1,024
  float*  b1ct    = (float*) (w + 23079936);     // 2,048
  char*   HSIM    = w + 23134208;                // 33,554,432 region
  double* hsim64  = (double*)HSIM;               //   phase A (16384*256*8 = 33.5MB)
  float*  hreg32  = (float*) HSIM;               //   phase B: 16,777,216
  float*  WcVr    = (float*)(HSIM + 16777216);   //   1,048,576
  float*  WcPr    = (float*)(HSIM + 17825792);   //   1,048,576
  float*  WcVPr   = (float*)(HSIM + 18874368);   //   1,048,576
  float*  Xvr     = (float*)(HSIM + 19922944);   //   1,048,576
  float*  Xpr     = (float*)(HSIM + 20971520);   //   65,536
  float*  bftop   = (float*) HSIM;               //   phase C: 8,388,608
  float*  vist    = (float*)(HSIM + 8388608);    //   4,194,304
  float*  Xvt     = (float*)(HSIM + 12582912);   //   2,097,152
  float*  Xpt     = (float*)(HSIM + 14680064);   //   131,072
  float*  hidnt   = (float*)(HSIM + 14811136);   //   2,097,152
  float*  WcVt    = (float*)(HSIM + 16908288);   //   2,097,152
  float*  WcPt    = (float*)(HSIM + 19005440);   //   2,097,152
  float*  WcVPt   = (float*)(HSIM + 21102592);   //   2,097,152

  // ---- stage 1: sim chain fp64 end-to-end (determines top-k) ----
  prep_sim64_kernel<<<Rc * HS / 256, 256, 0, stream>>>(
      sim_w1, sim_b1, WcV64, WcP64, WcVP64, b1c64);
  dgemm64_kernel<float, float, true, false, true><<<dim3(16, 16), 256, 0, stream>>>(
      box, ve_w1, ve_b1, H64, nullptr, 1024, Rc, Dc);
  dgemm64_kernel<double, float, true, false, false><<<dim3(16, 16), 256, 0, stream>>>(
      H64, ve_w2, ve_b2, vis64, nullptr, 1024, Rc, Rc);
  dgemm64_kernel<double, double, true, false, false><<<dim3(4, 16), 256, 0, stream>>>(
      vis64, WcV64, nullptr, Xv64, nullptr, 1024, HS, Rc);
  dgemm64_kernel<float, double, true, false, false><<<dim3(4, 1), 256, 0, stream>>>(
      phrase, WcP64, nullptr, Xp64, nullptr, BPc, HS, Rc);
  pair64_kernel<<<dim3(4, 256), 256, 0, stream>>>(
      vis64, phrase, WcVP64, Xv64, Xp64, b1c64, hsim64);
  layer2_sim64_kernel<<<PAIRS1 / 4, 256, 0, stream>>>(
      hsim64, sim_w2, sim_b2, simlog64, PAIRS1);
  softmax_topk64_kernel<<<BPc, 64, 0, stream>>>(simlog64, o_sim, topidx);

  // ---- stage 1: reg head in fp32 (value-only; hsim64 now dead) ----
  prep_reg32_kernel<<<Rc * HS / 256, 256, 0, stream>>>(
      reg_w1, reg_b1, WcVr, WcPr, WcVPr, b1cr);
  dgemm64_kernel<double, float, false, true, false><<<dim3(4, 16), 256, 0, stream>>>(
      vis64, WcVr, nullptr, nullptr, Xvr, 1024, HS, Rc);
  sgemm_kernel<64, 64, 32, 4, 4><<<dim3(4, 1), 256, 0, stream>>>(
      phrase, WcPr, nullptr, Xpr, BPc, HS, Rc, 0);
  pair_gemm_kernel<128, 128, 32, 8, 8, 1, HS, double><<<dim3(2, 128), 256, 0, stream>>>(
      vis64, phrase, WcVPr, Xvr, Xpr, b1cr, hreg32, PAIRS1);
  layer2_reg32_kernel<<<PAIRS1 / 4, 256, 0, stream>>>(
      hreg32, reg_w2, reg_b2, o_reg, PAIRS1);

  // ---- stage 2: all fp32 (indices fixed; thresholds loose) ----
  gather_kernel<<<PAIRS2, 256, 0, stream>>>(box, topidx, bftop);
  prep_t_kernel<<<Rc * HO / 256, 256, 0, stream>>>(
      simt_w1, regt_w1, simt_b1, regt_b1, WcVt, WcPt, WcVPt, b1ct);
  sgemm_kernel<128, 64, 32, 8, 4><<<dim3(16, 8), 256, 0, stream>>>(
      bftop, vet_w1, vet_b1, H1t, 1024, Rc, Dc, 1);
  sgemm_kernel<128, 64, 32, 8, 4><<<dim3(16, 8), 256, 0, stream>>>(
      H1t, vet_w2, vet_b2, vist, 1024, Rc, Rc, 0);
  sgemm_kernel<64, 64, 32, 4, 4><<<dim3(8, 16), 256, 0, stream>>>(
      vist, WcVt, nullptr, Xvt, 1024, HO, Rc, 0);
  sgemm_kernel<64, 64, 32, 4, 4><<<dim3(8, 1), 256, 0, stream>>>(
      phrase, WcPt, nullptr, Xpt, BPc, HO, Rc, 0);
  pair_gemm_kernel<64, 64, 32, 4, 4, 2, HO, float><<<dim3(8, 16), 256, 0, stream>>>(
      vist, phrase, WcVPt, Xvt, Xpt, b1ct, hidnt, PAIRS2);
  layer2_t_kernel<<<PAIRS2 / 4, 256, 0, stream>>>(
      hidnt, simt_w2, simt_b2, regt_w2, regt_b2, simtlog, o_regt, PAIRS2);
  softmax16_kernel<<<BPc, 64, 0, stream>>>(simtlog, o_simt);
}